// Round 2
// baseline (226.159 us; speedup 1.0000x reference)
//
#include <hip/hip_runtime.h>

// Problem constants (B=4, N=512, D_in=512, D_out=256), fp32 in/out.
constexpr int Bq   = 4;
constexpr int Nq   = 512;
constexpr int DIN  = 512;
constexpr int DOUT = 256;

// ---------------------------------------------------------------------------
// K0: WT[k][o] = W[o][k]  (512x256 <- 256x512), classic LDS tile transpose.
// grid (16,8), block (32,8). Coalesced read and write.
// ---------------------------------------------------------------------------
__global__ __launch_bounds__(256) void k0_wt(const float* __restrict__ W,
                                             float* __restrict__ WT) {
    __shared__ float tile[32][33];
    const int k0 = blockIdx.x * 32;   // over DIN=512
    const int o0 = blockIdx.y * 32;   // over DOUT=256
    const int tx = threadIdx.x;       // 32
    const int ty = threadIdx.y;       // 8
#pragma unroll
    for (int j = 0; j < 4; ++j)
        tile[ty + 8 * j][tx] = W[(o0 + ty + 8 * j) * DIN + k0 + tx];
    __syncthreads();
#pragma unroll
    for (int j = 0; j < 4; ++j)
        WT[(k0 + ty + 8 * j) * DOUT + o0 + tx] = tile[tx][ty + 8 * j];
}

// ---------------------------------------------------------------------------
// K1: Wh[b,n,o] = dot(H[b,n,:], WT[:,o]);  also WhT[b,o,n].
// grid 256 (8 rows each), block 512. r = t&7 (row), og = t>>3 (o quad).
// WT reads: 8 distinct float4 per wave, contiguous 128B -> 1-2 transactions.
// ---------------------------------------------------------------------------
__global__ __launch_bounds__(512) void k1_wh(const float* __restrict__ H,
                                             const float* __restrict__ WT,
                                             float* __restrict__ Wh,
                                             float* __restrict__ WhT) {
    const int t   = threadIdx.x;
    const int blk = blockIdx.x;           // 256
    const int b   = blk >> 6;
    const int n0  = (blk & 63) << 3;
    const int r   = t & 7;                // row within block
    const int og  = t >> 3;               // 0..63, o quad = 4*og

    const float4* __restrict__ h4  = (const float4*)(H + ((size_t)(b * Nq) + n0 + r) * DIN);
    const float4* __restrict__ wt4 = (const float4*)WT;   // [k][64 float4]

    float4 acc = make_float4(0.f, 0.f, 0.f, 0.f);

    for (int kc = 0; kc < DIN / 4; ++kc) {
        const float4 hv = h4[kc];
        const float4 w0 = wt4[(kc * 4 + 0) * 64 + og];
        const float4 w1 = wt4[(kc * 4 + 1) * 64 + og];
        const float4 w2 = wt4[(kc * 4 + 2) * 64 + og];
        const float4 w3 = wt4[(kc * 4 + 3) * 64 + og];
        acc.x += hv.x * w0.x + hv.y * w1.x + hv.z * w2.x + hv.w * w3.x;
        acc.y += hv.x * w0.y + hv.y * w1.y + hv.z * w2.y + hv.w * w3.y;
        acc.z += hv.x * w0.z + hv.y * w1.z + hv.z * w2.z + hv.w * w3.z;
        acc.w += hv.x * w0.w + hv.y * w1.w + hv.z * w2.w + hv.w * w3.w;
    }

    // Wh: coalesced float4 (wave covers 32 o x 8 rows)
    float4* whrow = (float4*)(Wh + ((size_t)(b * Nq) + n0 + r) * DOUT);
    whrow[og] = acc;

    // WhT[b][o][n0+r]: lanes r=0..7 contiguous per o -> 32B groups
    float* whT = WhT + (size_t)(b * DOUT) * Nq;
    whT[(4 * og + 0) * Nq + n0 + r] = acc.x;
    whT[(4 * og + 1) * Nq + n0 + r] = acc.y;
    whT[(4 * og + 2) * Nq + n0 + r] = acc.z;
    whT[(4 * og + 3) * Nq + n0 + r] = acc.w;
}

// ---------------------------------------------------------------------------
// K2: e + softmax -> P.
// e[i,j] = 0.6*(r_i + r_j) + 0.4 * sum_o a[o]*|Wh_i[o]+Wh_j[o]|,  r_n = a.Wh_n
// Block = (b, i0..i0+7), 1024 threads (16 waves/CU).
// Quarter q = t>>8 handles rows 2q, 2q+1; thread owns j pair {2jj, 2jj+1}.
// Inner loop: 1 coalesced float2 load : 10 VALU.
// ---------------------------------------------------------------------------
__global__ __launch_bounds__(1024) void k2_attn(const float* __restrict__ Wh,
                                                const float* __restrict__ WhT,
                                                const float* __restrict__ a,
                                                float* __restrict__ P) {
    const int t   = threadIdx.x;
    const int blk = blockIdx.x;           // 256
    const int b   = blk >> 6;
    const int i0  = (blk & 63) << 3;
    const int q   = __builtin_amdgcn_readfirstlane(t >> 8);   // 0..3, wave-uniform
    const int jj  = t & 255;
    const int r0  = 2 * q, r1 = 2 * q + 1;

    const float4* __restrict__ a4  = (const float4*)a;
    const float4* __restrict__ wi0 = (const float4*)(Wh + ((size_t)(b * Nq) + i0 + r0) * DOUT);
    const float4* __restrict__ wi1 = (const float4*)(Wh + ((size_t)(b * Nq) + i0 + r1) * DOUT);
    const float2* __restrict__ wt2 = (const float2*)(WhT + (size_t)(b * DOUT) * Nq) + jj;

    float racc0 = 0.f, racc1 = 0.f;
    float ab00 = 0.f, ab01 = 0.f, ab10 = 0.f, ab11 = 0.f;   // [row][j]

    for (int oc = 0; oc < DOUT / 4; ++oc) {
        const float4 av = a4[oc];
        const float4 w0 = wi0[oc];
        const float4 w1 = wi1[oc];
        const float* avp = (const float*)&av;
        const float* w0p = (const float*)&w0;
        const float* w1p = (const float*)&w1;
#pragma unroll
        for (int s = 0; s < 4; ++s) {
            const int   o   = oc * 4 + s;
            const float aq  = avp[s];
            const float wiA = w0p[s];
            const float wiB = w1p[s];
            const float2 wj = wt2[o * (Nq / 2)];
            racc0 += aq * wj.x;
            racc1 += aq * wj.y;
            ab00 += aq * fabsf(wiA + wj.x);
            ab01 += aq * fabsf(wiA + wj.y);
            ab10 += aq * fabsf(wiB + wj.x);
            ab11 += aq * fabsf(wiB + wj.y);
        }
    }

    // publish r_j (quarter 0 only; all quarters computed identical racc)
    __shared__ float rbuf[Nq];
    if (q == 0) ((float2*)rbuf)[jj] = make_float2(racc0, racc1);
    __syncthreads();

    const float ri0 = rbuf[i0 + r0];
    const float ri1 = rbuf[i0 + r1];
    float e00 = 0.6f * (ri0 + racc0) + 0.4f * ab00;
    float e01 = 0.6f * (ri0 + racc1) + 0.4f * ab01;
    float e10 = 0.6f * (ri1 + racc0) + 0.4f * ab10;
    float e11 = 0.6f * (ri1 + racc1) + 0.4f * ab11;

    // row softmax over 512 j: values for row r live in quarter r>>1 (4 waves)
    __shared__ float wred[2][8][4];
    const int wq   = (t >> 6) & 3;    // wave within quarter
    const int lane = t & 63;

    float m0 = fmaxf(e00, e01), m1 = fmaxf(e10, e11);
#pragma unroll
    for (int off = 32; off > 0; off >>= 1) {
        m0 = fmaxf(m0, __shfl_xor(m0, off));
        m1 = fmaxf(m1, __shfl_xor(m1, off));
    }
    if (lane == 0) { wred[0][r0][wq] = m0; wred[0][r1][wq] = m1; }
    __syncthreads();
    m0 = fmaxf(fmaxf(wred[0][r0][0], wred[0][r0][1]), fmaxf(wred[0][r0][2], wred[0][r0][3]));
    m1 = fmaxf(fmaxf(wred[0][r1][0], wred[0][r1][1]), fmaxf(wred[0][r1][2], wred[0][r1][3]));

    const float p00 = __expf(e00 - m0), p01 = __expf(e01 - m0);
    const float p10 = __expf(e10 - m1), p11 = __expf(e11 - m1);
    float s0 = p00 + p01, s1 = p10 + p11;
#pragma unroll
    for (int off = 32; off > 0; off >>= 1) {
        s0 += __shfl_xor(s0, off);
        s1 += __shfl_xor(s1, off);
    }
    if (lane == 0) { wred[1][r0][wq] = s0; wred[1][r1][wq] = s1; }
    __syncthreads();
    const float inv0 = 1.0f / (wred[1][r0][0] + wred[1][r0][1] + wred[1][r0][2] + wred[1][r0][3]);
    const float inv1 = 1.0f / (wred[1][r1][0] + wred[1][r1][1] + wred[1][r1][2] + wred[1][r1][3]);

    float2* prow0 = (float2*)(P + ((size_t)(b * Nq) + i0 + r0) * Nq);
    float2* prow1 = (float2*)(P + ((size_t)(b * Nq) + i0 + r1) * Nq);
    prow0[jj] = make_float2(p00 * inv0, p01 * inv0);
    prow1[jj] = make_float2(p10 * inv1, p11 * inv1);
}

// ---------------------------------------------------------------------------
// K3: out[b,i,o] = sum_j P[b,i,j] * Wh[b,j,o]
// Block = (b, i0..i0+7), 1024 threads. Group g = t>>7 (wave-uniform) -> row;
// oo = t&127 -> o pair. P rows scalar-loaded; Wh float2 coalesced.
// ---------------------------------------------------------------------------
__global__ __launch_bounds__(1024) void k3_av(const float* __restrict__ Wh,
                                              const float* __restrict__ P,
                                              float* __restrict__ out) {
    const int t   = threadIdx.x;
    const int blk = blockIdx.x;           // 256
    const int b   = blk >> 6;
    const int i0  = (blk & 63) << 3;
    const int g   = __builtin_amdgcn_readfirstlane(t >> 7);  // 0..7 row
    const int oo  = t & 127;                                  // o pair = {2oo, 2oo+1}

    const float2* __restrict__ wh2 = (const float2*)(Wh + (size_t)(b * Nq) * DOUT) + oo;
    const float4* __restrict__ p4  = (const float4*)(P + ((size_t)(b * Nq) + i0 + g) * Nq);

    float2 acc = make_float2(0.f, 0.f);

    for (int jc = 0; jc < Nq / 4; ++jc) {
        const float4 pv = p4[jc];
        const float2 w0 = wh2[(jc * 4 + 0) * (DOUT / 2)];
        const float2 w1 = wh2[(jc * 4 + 1) * (DOUT / 2)];
        const float2 w2 = wh2[(jc * 4 + 2) * (DOUT / 2)];
        const float2 w3 = wh2[(jc * 4 + 3) * (DOUT / 2)];
        acc.x += pv.x * w0.x + pv.y * w1.x + pv.z * w2.x + pv.w * w3.x;
        acc.y += pv.x * w0.y + pv.y * w1.y + pv.z * w2.y + pv.w * w3.y;
    }

    float2* o2 = (float2*)(out + ((size_t)(b * Nq) + i0 + g) * DOUT);
    o2[oo] = acc;
}

// ---------------------------------------------------------------------------
extern "C" void kernel_launch(void* const* d_in, const int* in_sizes, int n_in,
                              void* d_out, int out_size, void* d_ws, size_t ws_size,
                              hipStream_t stream) {
    const float* H = (const float*)d_in[0];   // [4,512,512]
    const float* W = (const float*)d_in[1];   // [256,512]
    const float* a = (const float*)d_in[2];   // [256,1]
    float* out = (float*)d_out;               // [4,512,256]

    float* Wh  = (float*)d_ws;                 // 2 MB
    float* WhT = Wh  + Bq * Nq * DOUT;         // 2 MB
    float* P   = WhT + Bq * Nq * DOUT;         // 4 MB
    float* WT  = P;                            // 0.5 MB, lifetime disjoint from P
                                               // (K0 writes, K1 reads, K2 overwrites)

    hipLaunchKernelGGL(k0_wt,   dim3(16, 8), dim3(32, 8), 0, stream, W, WT);
    hipLaunchKernelGGL(k1_wh,   dim3(256),   dim3(512),   0, stream, H, WT, Wh, WhT);
    hipLaunchKernelGGL(k2_attn, dim3(256),   dim3(1024),  0, stream, Wh, WhT, a, P);
    hipLaunchKernelGGL(k3_av,   dim3(256),   dim3(1024),  0, stream, Wh, P, out);
}

// Round 3
// 212.541 us; speedup vs baseline: 1.0641x; 1.0641x over previous
//
#include <hip/hip_runtime.h>

// Problem constants (B=4, N=512, D_in=512, D_out=256), fp32 in/out.
constexpr int Bq   = 4;
constexpr int Nq   = 512;
constexpr int DIN  = 512;
constexpr int DOUT = 256;

// ---------------------------------------------------------------------------
// K0: WT[k][o] = W[o][k]  (512x256 <- 256x512), classic LDS tile transpose.
// ---------------------------------------------------------------------------
__global__ __launch_bounds__(256) void k0_wt(const float* __restrict__ W,
                                             float* __restrict__ WT) {
    __shared__ float tile[32][33];
    const int k0 = blockIdx.x * 32;   // over DIN=512
    const int o0 = blockIdx.y * 32;   // over DOUT=256
    const int tx = threadIdx.x;       // 32
    const int ty = threadIdx.y;       // 8
#pragma unroll
    for (int j = 0; j < 4; ++j)
        tile[ty + 8 * j][tx] = W[(o0 + ty + 8 * j) * DIN + k0 + tx];
    __syncthreads();
#pragma unroll
    for (int j = 0; j < 4; ++j)
        WT[(k0 + ty + 8 * j) * DOUT + o0 + tx] = tile[tx][ty + 8 * j];
}

// ---------------------------------------------------------------------------
// K1: Wh[b,n,o] = dot(H[b,n,:], WT[:,o]);  also WhT[b,o,n].
// grid 256 (8 rows each), block 512. r = t&7 (row), og = t>>3 (o quad).
// Manual register prefetch: iteration kc computes with regs loaded at kc-1,
// so 5 loads/iter (x4 unroll) stay in flight across the FMA block.
// ---------------------------------------------------------------------------
__global__ __launch_bounds__(512) void k1_wh(const float* __restrict__ H,
                                             const float* __restrict__ WT,
                                             float* __restrict__ Wh,
                                             float* __restrict__ WhT) {
    const int t   = threadIdx.x;
    const int blk = blockIdx.x;           // 256
    const int b   = blk >> 6;
    const int n0  = (blk & 63) << 3;
    const int r   = t & 7;                // row within block
    const int og  = t >> 3;               // 0..63, o quad = 4*og

    const float4* __restrict__ h4  = (const float4*)(H + ((size_t)(b * Nq) + n0 + r) * DIN);
    const float4* __restrict__ wt4 = (const float4*)WT;   // [k][64 float4]

    constexpr int KC = DIN / 4;           // 128

    float4 acc = make_float4(0.f, 0.f, 0.f, 0.f);

    // prefetch registers for iteration 0
    float4 hv = h4[0];
    float4 w0 = wt4[0 * 64 + og];
    float4 w1 = wt4[1 * 64 + og];
    float4 w2 = wt4[2 * 64 + og];
    float4 w3 = wt4[3 * 64 + og];

#pragma unroll 4
    for (int kc = 0; kc < KC; ++kc) {
        const float4 chv = hv, c0 = w0, c1 = w1, c2 = w2, c3 = w3;
        const int kn = (kc + 1) & (KC - 1);          // wrap: last prefetch redundant
        hv = h4[kn];
        w0 = wt4[(kn * 4 + 0) * 64 + og];
        w1 = wt4[(kn * 4 + 1) * 64 + og];
        w2 = wt4[(kn * 4 + 2) * 64 + og];
        w3 = wt4[(kn * 4 + 3) * 64 + og];
        acc.x += chv.x * c0.x + chv.y * c1.x + chv.z * c2.x + chv.w * c3.x;
        acc.y += chv.x * c0.y + chv.y * c1.y + chv.z * c2.y + chv.w * c3.y;
        acc.z += chv.x * c0.z + chv.y * c1.z + chv.z * c2.z + chv.w * c3.z;
        acc.w += chv.x * c0.w + chv.y * c1.w + chv.z * c2.w + chv.w * c3.w;
    }

    // Wh: coalesced float4 (wave covers 32 o x 8 rows)
    float4* whrow = (float4*)(Wh + ((size_t)(b * Nq) + n0 + r) * DOUT);
    whrow[og] = acc;

    // WhT[b][o][n0+r]
    float* whT = WhT + (size_t)(b * DOUT) * Nq;
    whT[(4 * og + 0) * Nq + n0 + r] = acc.x;
    whT[(4 * og + 1) * Nq + n0 + r] = acc.y;
    whT[(4 * og + 2) * Nq + n0 + r] = acc.z;
    whT[(4 * og + 3) * Nq + n0 + r] = acc.w;
}

// ---------------------------------------------------------------------------
// K2: e + softmax -> P.
// e[i,j] = 0.6*(r_i + r_j) + 0.4 * sum_o a[o]*|Wh_i[o]+Wh_j[o]|,  r_n = a.Wh_n
// Block = (b, i0..i0+7), 1024 threads. Quarter q = t>>8 -> rows 2q,2q+1;
// thread owns j pair {2jj,2jj+1}. Manual prefetch of the 4 WhT float2 loads
// + the uniform a/Wh_i quads per oc iteration.
// ---------------------------------------------------------------------------
__global__ __launch_bounds__(1024) void k2_attn(const float* __restrict__ Wh,
                                                const float* __restrict__ WhT,
                                                const float* __restrict__ a,
                                                float* __restrict__ P) {
    const int t   = threadIdx.x;
    const int blk = blockIdx.x;           // 256
    const int b   = blk >> 6;
    const int i0  = (blk & 63) << 3;
    const int q   = __builtin_amdgcn_readfirstlane(t >> 8);   // 0..3, wave-uniform
    const int jj  = t & 255;
    const int r0  = 2 * q, r1 = 2 * q + 1;

    const float4* __restrict__ a4  = (const float4*)a;
    const float4* __restrict__ wi0 = (const float4*)(Wh + ((size_t)(b * Nq) + i0 + r0) * DOUT);
    const float4* __restrict__ wi1 = (const float4*)(Wh + ((size_t)(b * Nq) + i0 + r1) * DOUT);
    const float2* __restrict__ wt2 = (const float2*)(WhT + (size_t)(b * DOUT) * Nq) + jj;

    float racc0 = 0.f, racc1 = 0.f;
    float ab00 = 0.f, ab01 = 0.f, ab10 = 0.f, ab11 = 0.f;   // [row][j]

    constexpr int OC = DOUT / 4;          // 64

    // prefetch for oc = 0
    float4 av  = a4[0];
    float4 w0v = wi0[0];
    float4 w1v = wi1[0];
    float2 wj0 = wt2[0 * (Nq / 2)];
    float2 wj1 = wt2[1 * (Nq / 2)];
    float2 wj2 = wt2[2 * (Nq / 2)];
    float2 wj3 = wt2[3 * (Nq / 2)];

#pragma unroll 4
    for (int oc = 0; oc < OC; ++oc) {
        const float4 cav = av, cw0 = w0v, cw1 = w1v;
        const float2 cj0 = wj0, cj1 = wj1, cj2 = wj2, cj3 = wj3;

        const int ocn = (oc + 1) & (OC - 1);          // wrap
        av  = a4[ocn];
        w0v = wi0[ocn];
        w1v = wi1[ocn];
        wj0 = wt2[(ocn * 4 + 0) * (Nq / 2)];
        wj1 = wt2[(ocn * 4 + 1) * (Nq / 2)];
        wj2 = wt2[(ocn * 4 + 2) * (Nq / 2)];
        wj3 = wt2[(ocn * 4 + 3) * (Nq / 2)];

        const float* avp = (const float*)&cav;
        const float* w0p = (const float*)&cw0;
        const float* w1p = (const float*)&cw1;
        const float2 cj[4] = {cj0, cj1, cj2, cj3};
#pragma unroll
        for (int s = 0; s < 4; ++s) {
            const float aq  = avp[s];
            const float wiA = w0p[s];
            const float wiB = w1p[s];
            const float2 wj = cj[s];
            racc0 += aq * wj.x;
            racc1 += aq * wj.y;
            ab00 += aq * fabsf(wiA + wj.x);
            ab01 += aq * fabsf(wiA + wj.y);
            ab10 += aq * fabsf(wiB + wj.x);
            ab11 += aq * fabsf(wiB + wj.y);
        }
    }

    // publish r_j (quarter 0 only; all quarters computed identical racc)
    __shared__ float rbuf[Nq];
    if (q == 0) ((float2*)rbuf)[jj] = make_float2(racc0, racc1);
    __syncthreads();

    const float ri0 = rbuf[i0 + r0];
    const float ri1 = rbuf[i0 + r1];
    float e00 = 0.6f * (ri0 + racc0) + 0.4f * ab00;
    float e01 = 0.6f * (ri0 + racc1) + 0.4f * ab01;
    float e10 = 0.6f * (ri1 + racc0) + 0.4f * ab10;
    float e11 = 0.6f * (ri1 + racc1) + 0.4f * ab11;

    // row softmax over 512 j: values for row r live in quarter r>>1 (4 waves)
    __shared__ float wred[2][8][4];
    const int wq   = (t >> 6) & 3;    // wave within quarter
    const int lane = t & 63;

    float m0 = fmaxf(e00, e01), m1 = fmaxf(e10, e11);
#pragma unroll
    for (int off = 32; off > 0; off >>= 1) {
        m0 = fmaxf(m0, __shfl_xor(m0, off));
        m1 = fmaxf(m1, __shfl_xor(m1, off));
    }
    if (lane == 0) { wred[0][r0][wq] = m0; wred[0][r1][wq] = m1; }
    __syncthreads();
    m0 = fmaxf(fmaxf(wred[0][r0][0], wred[0][r0][1]), fmaxf(wred[0][r0][2], wred[0][r0][3]));
    m1 = fmaxf(fmaxf(wred[0][r1][0], wred[0][r1][1]), fmaxf(wred[0][r1][2], wred[0][r1][3]));

    const float p00 = __expf(e00 - m0), p01 = __expf(e01 - m0);
    const float p10 = __expf(e10 - m1), p11 = __expf(e11 - m1);
    float s0 = p00 + p01, s1 = p10 + p11;
#pragma unroll
    for (int off = 32; off > 0; off >>= 1) {
        s0 += __shfl_xor(s0, off);
        s1 += __shfl_xor(s1, off);
    }
    if (lane == 0) { wred[1][r0][wq] = s0; wred[1][r1][wq] = s1; }
    __syncthreads();
    const float inv0 = 1.0f / (wred[1][r0][0] + wred[1][r0][1] + wred[1][r0][2] + wred[1][r0][3]);
    const float inv1 = 1.0f / (wred[1][r1][0] + wred[1][r1][1] + wred[1][r1][2] + wred[1][r1][3]);

    float2* prow0 = (float2*)(P + ((size_t)(b * Nq) + i0 + r0) * Nq);
    float2* prow1 = (float2*)(P + ((size_t)(b * Nq) + i0 + r1) * Nq);
    prow0[jj] = make_float2(p00 * inv0, p01 * inv0);
    prow1[jj] = make_float2(p10 * inv1, p11 * inv1);
}

// ---------------------------------------------------------------------------
// K3: out[b,i,o] = sum_j P[b,i,j] * Wh[b,j,o]
// Block = (b, i0..i0+7), 1024 threads. g = t>>7 (wave-uniform row), oo = t&127
// (o pair). Manual prefetch of the 4 Wh float2 + uniform P float4 per jc.
// ---------------------------------------------------------------------------
__global__ __launch_bounds__(1024) void k3_av(const float* __restrict__ Wh,
                                              const float* __restrict__ P,
                                              float* __restrict__ out) {
    const int t   = threadIdx.x;
    const int blk = blockIdx.x;           // 256
    const int b   = blk >> 6;
    const int i0  = (blk & 63) << 3;
    const int g   = __builtin_amdgcn_readfirstlane(t >> 7);  // 0..7 row
    const int oo  = t & 127;                                  // o pair = {2oo, 2oo+1}

    const float2* __restrict__ wh2 = (const float2*)(Wh + (size_t)(b * Nq) * DOUT) + oo;
    const float4* __restrict__ p4  = (const float4*)(P + ((size_t)(b * Nq) + i0 + g) * Nq);

    constexpr int JC = Nq / 4;            // 128

    float2 acc = make_float2(0.f, 0.f);

    // prefetch for jc = 0
    float4 pv = p4[0];
    float2 w0 = wh2[0 * (DOUT / 2)];
    float2 w1 = wh2[1 * (DOUT / 2)];
    float2 w2 = wh2[2 * (DOUT / 2)];
    float2 w3 = wh2[3 * (DOUT / 2)];

#pragma unroll 4
    for (int jc = 0; jc < JC; ++jc) {
        const float4 cp = pv;
        const float2 c0 = w0, c1 = w1, c2 = w2, c3 = w3;
        const int jn = (jc + 1) & (JC - 1);           // wrap
        pv = p4[jn];
        w0 = wh2[(jn * 4 + 0) * (DOUT / 2)];
        w1 = wh2[(jn * 4 + 1) * (DOUT / 2)];
        w2 = wh2[(jn * 4 + 2) * (DOUT / 2)];
        w3 = wh2[(jn * 4 + 3) * (DOUT / 2)];
        acc.x += cp.x * c0.x + cp.y * c1.x + cp.z * c2.x + cp.w * c3.x;
        acc.y += cp.x * c0.y + cp.y * c1.y + cp.z * c2.y + cp.w * c3.y;
    }

    float2* o2 = (float2*)(out + ((size_t)(b * Nq) + i0 + g) * DOUT);
    o2[oo] = acc;
}

// ---------------------------------------------------------------------------
extern "C" void kernel_launch(void* const* d_in, const int* in_sizes, int n_in,
                              void* d_out, int out_size, void* d_ws, size_t ws_size,
                              hipStream_t stream) {
    const float* H = (const float*)d_in[0];   // [4,512,512]
    const float* W = (const float*)d_in[1];   // [256,512]
    const float* a = (const float*)d_in[2];   // [256,1]
    float* out = (float*)d_out;               // [4,512,256]

    float* Wh  = (float*)d_ws;                 // 2 MB
    float* WhT = Wh  + Bq * Nq * DOUT;         // 2 MB
    float* P   = WhT + Bq * Nq * DOUT;         // 4 MB
    float* WT  = P;                            // 0.5 MB, lifetime disjoint from P

    hipLaunchKernelGGL(k0_wt,   dim3(16, 8), dim3(32, 8), 0, stream, W, WT);
    hipLaunchKernelGGL(k1_wh,   dim3(256),   dim3(512),   0, stream, H, WT, Wh, WhT);
    hipLaunchKernelGGL(k2_attn, dim3(256),   dim3(1024),  0, stream, Wh, WhT, a, P);
    hipLaunchKernelGGL(k3_av,   dim3(256),   dim3(1024),  0, stream, Wh, P, out);
}